// Round 3
// baseline (1493.392 us; speedup 1.0000x reference)
//
#include <hip/hip_runtime.h>

// Problem dims (from setup_inputs): x[B,T,I], W[H,I], b[H]
// B=32, T=2048, I=512, H=1024.
// out = spikes[B,T,H] fp32, then v_f[B,H], then i_f[B,H].

static constexpr int BM = 128, BN = 128, BK = 16;

// ---------------------------------------------------------------------------
// Kernel 1: current[m,n] = sum_k X[m,k] * W[n,k] + bias[n]
// fp32, tiled, LDS double-buffered. M=65536, N=1024, K=512.
// ---------------------------------------------------------------------------
__global__ __launch_bounds__(256) void snn_gemm_f32(
    const float* __restrict__ X,    // [M,K]
    const float* __restrict__ Wt,   // [N,K]
    const float* __restrict__ bias, // [N]
    float* __restrict__ C,          // [M,N]
    int M, int N, int K)
{
    __shared__ float As[2][BK][BM + 4];
    __shared__ float Bs[2][BK][BN + 4];

    const int tid   = threadIdx.x;
    const int mBase = blockIdx.y * BM;
    const int nBase = blockIdx.x * BN;

    // loader mapping: each thread brings 2 float4 of A and 2 float4 of B
    const int row0 = tid >> 2;         // 0..63
    const int kq   = (tid & 3) * 4;    // 0,4,8,12 (k offset of the float4)
    const int row1 = row0 + 64;

    // compute mapping: 16x16 threads, 8x8 micro-tile (split 4+4 at +64)
    const int tx = tid & 15;
    const int ty = tid >> 4;

    const float* Xp = X + (size_t)mBase * K;
    const float* Wp = Wt + (size_t)nBase * K;

    float acc[8][8];
#pragma unroll
    for (int i = 0; i < 8; ++i)
#pragma unroll
        for (int j = 0; j < 8; ++j) acc[i][j] = 0.f;

    float4 ra0, ra1, rb0, rb1;

    // prologue: k-tile 0 -> buffer 0
    ra0 = *(const float4*)(Xp + (size_t)row0 * K + kq);
    ra1 = *(const float4*)(Xp + (size_t)row1 * K + kq);
    rb0 = *(const float4*)(Wp + (size_t)row0 * K + kq);
    rb1 = *(const float4*)(Wp + (size_t)row1 * K + kq);

    As[0][kq + 0][row0] = ra0.x; As[0][kq + 1][row0] = ra0.y;
    As[0][kq + 2][row0] = ra0.z; As[0][kq + 3][row0] = ra0.w;
    As[0][kq + 0][row1] = ra1.x; As[0][kq + 1][row1] = ra1.y;
    As[0][kq + 2][row1] = ra1.z; As[0][kq + 3][row1] = ra1.w;
    Bs[0][kq + 0][row0] = rb0.x; Bs[0][kq + 1][row0] = rb0.y;
    Bs[0][kq + 2][row0] = rb0.z; Bs[0][kq + 3][row0] = rb0.w;
    Bs[0][kq + 0][row1] = rb1.x; Bs[0][kq + 1][row1] = rb1.y;
    Bs[0][kq + 2][row1] = rb1.z; Bs[0][kq + 3][row1] = rb1.w;
    __syncthreads();

    const int nk = K / BK; // 32
#pragma unroll 1
    for (int kt = 0; kt < nk; ++kt) {
        const int cur = kt & 1;
        if (kt + 1 < nk) {
            const int k0 = (kt + 1) * BK;
            ra0 = *(const float4*)(Xp + (size_t)row0 * K + k0 + kq);
            ra1 = *(const float4*)(Xp + (size_t)row1 * K + k0 + kq);
            rb0 = *(const float4*)(Wp + (size_t)row0 * K + k0 + kq);
            rb1 = *(const float4*)(Wp + (size_t)row1 * K + k0 + kq);
        }
#pragma unroll
        for (int kk = 0; kk < BK; ++kk) {
            float a[8], bv[8];
            *(float4*)&a[0]  = *(const float4*)&As[cur][kk][ty * 4];
            *(float4*)&a[4]  = *(const float4*)&As[cur][kk][ty * 4 + 64];
            *(float4*)&bv[0] = *(const float4*)&Bs[cur][kk][tx * 4];
            *(float4*)&bv[4] = *(const float4*)&Bs[cur][kk][tx * 4 + 64];
#pragma unroll
            for (int i = 0; i < 8; ++i)
#pragma unroll
                for (int j = 0; j < 8; ++j)
                    acc[i][j] = fmaf(a[i], bv[j], acc[i][j]);
        }
        if (kt + 1 < nk) {
            const int nxt = cur ^ 1;
            As[nxt][kq + 0][row0] = ra0.x; As[nxt][kq + 1][row0] = ra0.y;
            As[nxt][kq + 2][row0] = ra0.z; As[nxt][kq + 3][row0] = ra0.w;
            As[nxt][kq + 0][row1] = ra1.x; As[nxt][kq + 1][row1] = ra1.y;
            As[nxt][kq + 2][row1] = ra1.z; As[nxt][kq + 3][row1] = ra1.w;
            Bs[nxt][kq + 0][row0] = rb0.x; Bs[nxt][kq + 1][row0] = rb0.y;
            Bs[nxt][kq + 2][row0] = rb0.z; Bs[nxt][kq + 3][row0] = rb0.w;
            Bs[nxt][kq + 0][row1] = rb1.x; Bs[nxt][kq + 1][row1] = rb1.y;
            Bs[nxt][kq + 2][row1] = rb1.z; Bs[nxt][kq + 3][row1] = rb1.w;
        }
        __syncthreads();
    }

    // epilogue: bias + store
    const float4 bb0 = *(const float4*)(bias + nBase + tx * 4);
    const float4 bb1 = *(const float4*)(bias + nBase + tx * 4 + 64);
#pragma unroll
    for (int i = 0; i < 8; ++i) {
        const int m = mBase + ty * 4 + (i & 3) + ((i >> 2) << 6);
        float4 o0, o1;
        o0.x = acc[i][0] + bb0.x; o0.y = acc[i][1] + bb0.y;
        o0.z = acc[i][2] + bb0.z; o0.w = acc[i][3] + bb0.w;
        o1.x = acc[i][4] + bb1.x; o1.y = acc[i][5] + bb1.y;
        o1.z = acc[i][6] + bb1.z; o1.w = acc[i][7] + bb1.w;
        *(float4*)(C + (size_t)m * N + nBase + tx * 4)      = o0;
        *(float4*)(C + (size_t)m * N + nBase + tx * 4 + 64) = o1;
    }
}

// ---------------------------------------------------------------------------
// Kernel 2: sequential LIF scan over T per neuron (b,h).
// cur may alias spk (in-place): z_t does not depend on c_t, and within a
// thread every read of element t precedes every write to element t; threads
// touch disjoint (b,h) columns, so in-place is race-free.
// U=32 prefetch depth: 32768 threads x 32 x 4B = 4MB in flight > 2.4MB
// BW-latency product (6.3 TB/s x ~375ns).
// ---------------------------------------------------------------------------
__global__ __launch_bounds__(64) void snn_scan(
    const float* cur, float* spk, float* vf, float* iff,
    int T, int H)
{
    const int idx = blockIdx.x * blockDim.x + threadIdx.x; // 0..B*H-1
    const int h = idx & (H - 1);
    const int b = idx >> 10; // H = 1024
    const size_t base = ((size_t)b * T) * H + h;

    constexpr int U = 32;
    float ca[U];
#pragma unroll
    for (int j = 0; j < U; ++j) ca[j] = cur[base + (size_t)j * H];

    float v = 0.f, ii = 0.f;
    for (int t0 = 0; t0 < T; t0 += U) {
        float cb[U];
        const bool pref = (t0 + U) < T;
#pragma unroll
        for (int j = 0; j < U; ++j)
            cb[j] = pref ? cur[base + (size_t)(t0 + U + j) * H] : 0.f;
#pragma unroll
        for (int j = 0; j < U; ++j) {
            const float v_dec = v + 0.1f * ((0.0f - v) + ii);
            const float i_dec = ii - 0.2f * ii;
            const float z = (v_dec > 1.0f) ? 1.0f : 0.0f;
            v  = (v_dec > 1.0f) ? 0.0f : v_dec;
            ii = i_dec + ca[j];
            spk[base + (size_t)(t0 + j) * H] = z;
        }
#pragma unroll
        for (int j = 0; j < U; ++j) ca[j] = cb[j];
    }
    vf[idx]  = v;
    iff[idx] = ii;
}

// ---------------------------------------------------------------------------
extern "C" void kernel_launch(void* const* d_in, const int* in_sizes, int n_in,
                              void* d_out, int out_size, void* d_ws, size_t ws_size,
                              hipStream_t stream) {
    const int B = 32, T = 2048, I = 512, H = 1024;
    const int M = B * T, N = H, K = I;

    const float* x    = (const float*)d_in[0];
    const float* W    = (const float*)d_in[1];
    const float* bias = (const float*)d_in[2];

    float* out    = (float*)d_out;
    float* spikes = out;                        // [B,T,H]
    float* vf     = out + (size_t)B * T * H;    // [B,H]
    float* iff    = vf + (size_t)B * H;         // [B,H]

    const size_t curBytes = (size_t)B * T * H * sizeof(float);
    float* curbuf = (ws_size >= curBytes) ? (float*)d_ws : spikes;

    dim3 grid(N / BN, M / BM); // (8, 512)
    snn_gemm_f32<<<grid, 256, 0, stream>>>(x, W, bias, curbuf, M, N, K);

    const int nNeuron = B * H; // 32768
    snn_scan<<<nNeuron / 64, 64, 0, stream>>>(curbuf, spikes, vf, iff, T, H);
}